// Round 4
// baseline (31.011 us; speedup 1.0000x reference)
//
#include <hip/hip_runtime.h>
#include <math.h>

// SentAttNet: scores = tanh(x[b,s,:]·w + bias); attn = masked softmax over S.
// B=4096 rows, S=2048, F=4 (one float4 per (b,s)).
// Memory-bound: 134 MB in + 33.5 MB out, each touched exactly once.
// Structure: one WAVE per row (4 independent waves per 256-thread block).
// No LDS, no __syncthreads — row reduction is a pure wave64 shuffle
// butterfly, so no wave ever waits on another. NT hints on both streams.
// NOTE: __builtin_nontemporal_load needs a clang ext_vector_type, not
// HIP's float4 struct.

#define S_LEN 2048
#define WAVES_PER_BLOCK 4
#define BLOCK (WAVES_PER_BLOCK * 64)
#define PER_LANE (S_LEN / 64)  // 32

typedef float floatv4 __attribute__((ext_vector_type(4)));

__device__ __forceinline__ float fast_tanh(float z) {
    // tanh(z) = (e^{2z} - 1) / (e^{2z} + 1); clamp so e^{2z} can't overflow.
    z = fminf(fmaxf(z, -20.0f), 20.0f);
    const float t2 = __expf(2.0f * z);
    return (t2 - 1.0f) * __builtin_amdgcn_rcpf(t2 + 1.0f);
}

// 2nd launch_bounds arg = min waves/EU; for 256-thread blocks this is
// blocks/CU. 4 -> 16 waves/CU, VGPR budget <=128 (e[32]+pipeline fits).
__global__ __launch_bounds__(BLOCK, 4) void sent_att_kernel(
    const float* __restrict__ x,     // [B, S, 4]
    const float* __restrict__ w,     // [4, 1]
    const float* __restrict__ bias,  // [1]
    float* __restrict__ out)         // [B, S]
{
    const int wave = threadIdx.x >> 6;
    const int lane = threadIdx.x & 63;
    const int b = blockIdx.x * WAVES_PER_BLOCK + wave;

    const floatv4* __restrict__ xrow =
        reinterpret_cast<const floatv4*>(x) + (size_t)b * S_LEN;

    const float w0 = w[0], w1 = w[1], w2 = w[2], w3 = w[3];
    const float cb = bias[0];

    // Single pass: load (1 KB/wave/instr, coalesced), score, exp — registers.
    float e[PER_LANE];
    float lsum = 0.0f;
#pragma unroll
    for (int k = 0; k < PER_LANE; ++k) {
        const floatv4 v = __builtin_nontemporal_load(&xrow[lane + k * 64]);
        const float z = v.x * w0 + v.y * w1 + v.z * w2 + v.w * w3 + cb;
        const float sv = fast_tanh(z);
        // tanh bounded in [-1,1] -> exp in [0.37, 2.72]: no max-shift needed.
        const float ev = (sv != 0.0f) ? __expf(sv) : 0.0f;
        e[k] = ev;
        lsum += ev;
    }

    // Wave64 butterfly sum — no LDS, no barrier.
#pragma unroll
    for (int off = 32; off > 0; off >>= 1)
        lsum += __shfl_xor(lsum, off, 64);
    const float inv = 1.0f / lsum;

    // Coalesced normalized writes (256 B/wave/instr), streaming.
    float* __restrict__ orow = out + (size_t)b * S_LEN;
#pragma unroll
    for (int k = 0; k < PER_LANE; ++k)
        __builtin_nontemporal_store(e[k] * inv, &orow[lane + k * 64]);
}

extern "C" void kernel_launch(void* const* d_in, const int* in_sizes, int n_in,
                              void* d_out, int out_size, void* d_ws, size_t ws_size,
                              hipStream_t stream) {
    const float* x    = (const float*)d_in[0];  // [B, S, F]
    const float* w    = (const float*)d_in[1];  // [F, 1]
    const float* bias = (const float*)d_in[2];  // [1]
    float* out = (float*)d_out;                 // [B, S]

    const int B = in_sizes[0] / (S_LEN * 4);    // 4096
    sent_att_kernel<<<B / WAVES_PER_BLOCK, BLOCK, 0, stream>>>(x, w, bias, out);
}

// Round 5
// 29.114 us; speedup vs baseline: 1.0651x; 1.0651x over previous
//
#include <hip/hip_runtime.h>
#include <math.h>

// SentAttNet: scores = tanh(x[b,s,:]·w + bias); attn = masked softmax over S.
// B=4096 rows, S=2048, F=4 (one float4 per (b,s)). One block per row.
// Memory-bound: 134 MB in + 33.5 MB out, each touched once.
// R5 = R2 structure (block-per-row, e[8]/thread, single LDS sum reduction,
// REGULAR cacheable loads — x may be L3-resident across graph replays)
// + nontemporal STORES only (out is write-once, never re-read by us).

#define S_LEN 2048
#define BLOCK 256
#define PER_THREAD (S_LEN / BLOCK)  // 8

__device__ __forceinline__ float fast_tanh(float z) {
    // tanh(z) = (e^{2z} - 1) / (e^{2z} + 1); clamp so e^{2z} can't overflow.
    z = fminf(fmaxf(z, -20.0f), 20.0f);
    const float t2 = __expf(2.0f * z);
    return (t2 - 1.0f) * __builtin_amdgcn_rcpf(t2 + 1.0f);
}

__global__ __launch_bounds__(BLOCK) void sent_att_kernel(
    const float* __restrict__ x,     // [B, S, 4]
    const float* __restrict__ w,     // [4, 1]
    const float* __restrict__ bias,  // [1]
    float* __restrict__ out)         // [B, S]
{
    const int b = blockIdx.x;
    const int t = threadIdx.x;
    const float4* __restrict__ xrow =
        reinterpret_cast<const float4*>(x) + (size_t)b * S_LEN;

    const float w0 = w[0], w1 = w[1], w2 = w[2], w3 = w[3];
    const float cb = bias[0];

    // Single pass: load, score, exp, mask — all in registers.
    float e[PER_THREAD];
    float lsum = 0.0f;
#pragma unroll
    for (int k = 0; k < PER_THREAD; ++k) {
        const int s = t + k * BLOCK;             // coalesced float4 loads
        const float4 v = xrow[s];
        const float z = v.x * w0 + v.y * w1 + v.z * w2 + v.w * w3 + cb;
        const float sv = fast_tanh(z);
        // tanh bounded in [-1,1] -> exp in [0.37, 2.72]: no max-shift needed.
        const float ev = (sv != 0.0f) ? __expf(sv) : 0.0f;
        e[k] = ev;
        lsum += ev;
    }

    // Block-reduce sum (wave64 butterfly + 4-entry LDS)
#pragma unroll
    for (int off = 32; off > 0; off >>= 1)
        lsum += __shfl_xor(lsum, off, 64);

    __shared__ float ssum[BLOCK / 64];
    const int wave = t >> 6;
    const int lane = t & 63;
    if (lane == 0) ssum[wave] = lsum;
    __syncthreads();
    const float total = ssum[0] + ssum[1] + ssum[2] + ssum[3];
    const float inv = 1.0f / total;

    // Coalesced normalized writes, streamed (write-once, never re-read).
    float* __restrict__ orow = out + (size_t)b * S_LEN;
#pragma unroll
    for (int k = 0; k < PER_THREAD; ++k)
        __builtin_nontemporal_store(e[k] * inv, &orow[t + k * BLOCK]);
}

extern "C" void kernel_launch(void* const* d_in, const int* in_sizes, int n_in,
                              void* d_out, int out_size, void* d_ws, size_t ws_size,
                              hipStream_t stream) {
    const float* x    = (const float*)d_in[0];  // [B, S, F]
    const float* w    = (const float*)d_in[1];  // [F, 1]
    const float* bias = (const float*)d_in[2];  // [1]
    float* out = (float*)d_out;                 // [B, S]

    const int B = in_sizes[0] / (S_LEN * 4);    // 4096
    sent_att_kernel<<<B, BLOCK, 0, stream>>>(x, w, bias, out);
}